// Round 2
// baseline (1056.164 us; speedup 1.0000x reference)
//
#include <hip/hip_runtime.h>
#include <hip/hip_bf16.h>

// Problem constants
#define B_  2
#define V_  4
#define Hin 480
#define Win 640
#define H2  240   // after conv1 (s2)
#define W2  320
#define H4  120   // after conv2 (s2)
#define W4  160
#define C1  32
#define C_  64
#define D_  5
#define NIMG 10  // B + B*V

// ---------------- workspace layout (float offsets) ----------------
// feat1 (NCHW, 10x32x240x320) @ 0                     : 24,576,000
// feat2 (NCHW, 10x64x120x160) @ 24,576,000            : 12,288,000
// feat3 (NHWC, 10x120x160x64) @ 0  (overlaps feat1)   : 12,288,000
// geom  (8 x 12)              @ 36,864,000            : 96
// w1t                         @ 36,864,128            : 4,704
// w2t                         @ 36,868,864            : 18,432
// w3t                         @ 36,887,296            : 36,864
// total ~ 36,924,160 floats = 147.7 MB
#define OFF_F1   0
#define OFF_F2   24576000
#define OFF_F3   0
#define OFF_GEOM 36864000
#define OFF_W1T  36864128
#define OFF_W2T  36868864
#define OFF_W3T  36887296

// ---------------- weight transpose: [co][ci][kh][kw] -> [ci][kh][kw][co] ----
__global__ void tw_kernel(const float* __restrict__ w, float* __restrict__ wt,
                          int CO, int CI, int KH, int KW) {
    int idx = blockIdx.x * 256 + threadIdx.x;
    int total = CO * CI * KH * KW;
    if (idx >= total) return;
    int co = idx % CO;
    int r = idx / CO;
    int kx = r % KW; r /= KW;
    int ky = r % KH; r /= KH;
    int ci = r;
    wt[idx] = w[((co * CI + ci) * KH + ky) * KW + kx];
}

// ---------------- geometry: A = K R Kinv, c = K t ----------------
__global__ void geom_kernel(const float* __restrict__ poses,
                            const float* __restrict__ Kmat,
                            float* __restrict__ geom) {
    int i = threadIdx.x;         // (b*V + v)
    if (i >= B_ * V_) return;
    int b = i / V_;
    const float* Kb = Kmat + b * 9;
    float k00=Kb[0],k01=Kb[1],k02=Kb[2];
    float k10=Kb[3],k11=Kb[4],k12=Kb[5];
    float k20=Kb[6],k21=Kb[7],k22=Kb[8];
    float det = k00*(k11*k22-k12*k21) - k01*(k10*k22-k12*k20) + k02*(k10*k21-k11*k20);
    float id = 1.0f / det;
    float ki[9];
    ki[0]=(k11*k22-k12*k21)*id; ki[1]=(k02*k21-k01*k22)*id; ki[2]=(k01*k12-k02*k11)*id;
    ki[3]=(k12*k20-k10*k22)*id; ki[4]=(k00*k22-k02*k20)*id; ki[5]=(k02*k10-k00*k12)*id;
    ki[6]=(k10*k21-k11*k20)*id; ki[7]=(k01*k20-k00*k21)*id; ki[8]=(k00*k11-k01*k10)*id;
    const float* P = poses + i * 16;
    float R[9] = {P[0],P[1],P[2], P[4],P[5],P[6], P[8],P[9],P[10]};
    float t[3] = {P[3],P[7],P[11]};
    float KR[9];
    for (int r = 0; r < 3; r++)
        for (int c = 0; c < 3; c++)
            KR[r*3+c] = Kb[r*3+0]*R[0*3+c] + Kb[r*3+1]*R[1*3+c] + Kb[r*3+2]*R[2*3+c];
    float* g = geom + i * 12;
    for (int r = 0; r < 3; r++)
        for (int c = 0; c < 3; c++)
            g[r*3+c] = KR[r*3+0]*ki[0*3+c] + KR[r*3+1]*ki[1*3+c] + KR[r*3+2]*ki[2*3+c];
    for (int r = 0; r < 3; r++)
        g[9+r] = Kb[r*3+0]*t[0] + Kb[r*3+1]*t[1] + Kb[r*3+2]*t[2];
}

// ---------------- conv1: 3->32, 7x7, s2, p3, ReLU. out NCHW ----------------
__global__ void conv1_kernel(const float* __restrict__ ref, const float* __restrict__ ngh,
                             const float* __restrict__ w1t, const float* __restrict__ b1,
                             float* __restrict__ out) {
    const int ox = blockIdx.x * 16 + threadIdx.x;
    const int oy = blockIdx.y * 16 + threadIdx.y;
    const int n  = blockIdx.z;
    const float* in = (n < B_) ? (ref + (size_t)n * 3 * Hin * Win)
                               : (ngh + (size_t)(n - B_) * 3 * Hin * Win);
    float acc[C1];
#pragma unroll
    for (int co = 0; co < C1; co++) acc[co] = b1[co];
    for (int ci = 0; ci < 3; ci++) {
        for (int ky = 0; ky < 7; ky++) {
            int iy = oy * 2 - 3 + ky;
            if (iy < 0 || iy >= Hin) continue;
            const float* row = in + ((size_t)ci * Hin + iy) * Win;
            for (int kx = 0; kx < 7; kx++) {
                int ix = ox * 2 - 3 + kx;
                float val = (ix >= 0 && ix < Win) ? row[ix] : 0.0f;
                const float* wp = w1t + ((ci * 7 + ky) * 7 + kx) * C1;
#pragma unroll
                for (int co = 0; co < C1; co++) acc[co] += val * wp[co];
            }
        }
    }
#pragma unroll
    for (int co = 0; co < C1; co++)
        out[(((size_t)n * C1 + co) * H2 + oy) * W2 + ox] = fmaxf(acc[co], 0.0f);
}

// ---------------- conv2: 32->64, 3x3, s2, p1, ReLU. out NCHW ----------------
__global__ void conv2_kernel(const float* __restrict__ in, const float* __restrict__ w2t,
                             const float* __restrict__ b2, float* __restrict__ out) {
    const int ox = blockIdx.x * 16 + threadIdx.x;
    const int oy = blockIdx.y * 16 + threadIdx.y;
    const int n  = blockIdx.z;
    if (oy >= H4) return;
    const float* inp = in + (size_t)n * C1 * H2 * W2;
    float acc[C_];
#pragma unroll
    for (int co = 0; co < C_; co++) acc[co] = b2[co];
    for (int ci = 0; ci < C1; ci++) {
        const float* icp = inp + (size_t)ci * H2 * W2;
#pragma unroll
        for (int ky = 0; ky < 3; ky++) {
            int iy = oy * 2 - 1 + ky;
            if (iy < 0 || iy >= H2) continue;
            const float* row = icp + (size_t)iy * W2;
#pragma unroll
            for (int kx = 0; kx < 3; kx++) {
                int ix = ox * 2 - 1 + kx;
                float val = (ix >= 0 && ix < W2) ? row[ix] : 0.0f;
                const float* wp = w2t + ((ci * 3 + ky) * 3 + kx) * C_;
#pragma unroll
                for (int co = 0; co < C_; co++) acc[co] += val * wp[co];
            }
        }
    }
#pragma unroll
    for (int co = 0; co < C_; co++)
        out[(((size_t)n * C_ + co) * H4 + oy) * W4 + ox] = fmaxf(acc[co], 0.0f);
}

// ---------------- conv3: 64->64, 3x3, s1, p1, no act. out NHWC --------------
__global__ void conv3_kernel(const float* __restrict__ in, const float* __restrict__ w3t,
                             const float* __restrict__ b3, float* __restrict__ out) {
    const int ox = blockIdx.x * 16 + threadIdx.x;
    const int oy = blockIdx.y * 16 + threadIdx.y;
    const int n  = blockIdx.z;
    if (oy >= H4) return;
    const float* inp = in + (size_t)n * C_ * H4 * W4;
    float acc[C_];
#pragma unroll
    for (int co = 0; co < C_; co++) acc[co] = b3[co];
    for (int ci = 0; ci < C_; ci++) {
        const float* icp = inp + (size_t)ci * H4 * W4;
#pragma unroll
        for (int ky = 0; ky < 3; ky++) {
            int iy = oy - 1 + ky;
            if (iy < 0 || iy >= H4) continue;
            const float* row = icp + (size_t)iy * W4;
#pragma unroll
            for (int kx = 0; kx < 3; kx++) {
                int ix = ox - 1 + kx;
                float val = (ix >= 0 && ix < W4) ? row[ix] : 0.0f;
                const float* wp = w3t + ((ci * 3 + ky) * 3 + kx) * C_;
#pragma unroll
                for (int co = 0; co < C_; co++) acc[co] += val * wp[co];
            }
        }
    }
    float* op = out + (((size_t)n * H4 + oy) * W4 + ox) * C_;
#pragma unroll
    for (int co = 0; co < C_; co++) op[co] = acc[co];
}

// ---------------- warp + cost volume. one wave per (b,h,w) ----------------
__global__ void warpcost_kernel(const float* __restrict__ feat,  // NHWC, 10 imgs
                                const float* __restrict__ geom,
                                const float* __restrict__ dc,    // (B,D,H4,W4)
                                const int*   __restrict__ valid, // B*V ints
                                float* __restrict__ out) {
    const int wave = threadIdx.x >> 6;
    const int lane = threadIdx.x & 63;
    int pid = blockIdx.x * 4 + wave;  // 0 .. B*H4*W4-1
    int b = pid / (H4 * W4);
    int rem = pid % (H4 * W4);
    int h = rem / W4;
    int w = rem % W4;

    const float refc = feat[(((size_t)b * H4 + h) * W4 + w) * C_ + lane];

    float accv[D_] = {0.f, 0.f, 0.f, 0.f, 0.f};
    float den[D_]  = {0.f, 0.f, 0.f, 0.f, 0.f};

    for (int v = 0; v < V_; v++) {
        if (!valid[b * V_ + v]) continue;
        const float* g = geom + (b * V_ + v) * 12;
        float rx = g[0] * w + g[1] * h + g[2];
        float ry = g[3] * w + g[4] * h + g[5];
        float rz = g[6] * w + g[7] * h + g[8];
        float c0 = g[9], c1 = g[10], c2 = g[11];
        const float* fimg = feat + (size_t)(B_ + b * V_ + v) * H4 * W4 * C_;
#pragma unroll
        for (int d = 0; d < D_; d++) {
            float dep = dc[(((size_t)b * D_ + d) * H4 + h) * W4 + w];
            float px = dep * rx + c0;
            float py = dep * ry + c1;
            float pz = dep * rz + c2;
            bool zok = pz > 0.001f;
            float zc = fmaxf(pz, 0.001f);
            float u  = px / zc;
            float vv = py / zc;
            bool inb = (u >= 0.f) && (u <= (float)(W4 - 1)) &&
                       (vv >= 0.f) && (vv <= (float)(H4 - 1));
            if (zok && inb) {   // wave-uniform branch
                float u0f = floorf(u), v0f = floorf(vv);
                float du = u - u0f, dv = vv - v0f;
                int u0 = (int)u0f, v0 = (int)v0f;
                int u1 = min(u0 + 1, W4 - 1), v1 = min(v0 + 1, H4 - 1);
                const float* r00 = fimg + ((size_t)v0 * W4 + u0) * C_;
                const float* r01 = fimg + ((size_t)v0 * W4 + u1) * C_;
                const float* r10 = fimg + ((size_t)v1 * W4 + u0) * C_;
                const float* r11 = fimg + ((size_t)v1 * W4 + u1) * C_;
                float f00 = r00[lane], f01 = r01[lane];
                float f10 = r10[lane], f11 = r11[lane];
                float wa = (1.f - du) * (1.f - dv);
                float wb = du * (1.f - dv);
                float wc = (1.f - du) * dv;
                float wd = du * dv;
                accv[d] += f00 * wa + f01 * wb + f10 * wc + f11 * wd;
                den[d]  += 1.f;
            }
        }
    }

#pragma unroll
    for (int d = 0; d < D_; d++) {
        float s = refc * accv[d];
        for (int off = 32; off > 0; off >>= 1) s += __shfl_xor(s, off, 64);
        if (lane == 0) {
            out[(((size_t)b * D_ + d) * H4 + h) * W4 + w] =
                (s * (1.0f / (float)C_)) / fmaxf(den[d], 1.0f);
        }
    }
}

extern "C" void kernel_launch(void* const* d_in, const int* in_sizes, int n_in,
                              void* d_out, int out_size, void* d_ws, size_t ws_size,
                              hipStream_t stream) {
    const float* ref_img  = (const float*)d_in[0];
    const float* ngh_img  = (const float*)d_in[1];
    const float* poses    = (const float*)d_in[2];
    const int*   is_valid = (const int*)  d_in[3];
    const float* K        = (const float*)d_in[4];
    const float* dc       = (const float*)d_in[5];
    const float* w1 = (const float*)d_in[6];
    const float* b1 = (const float*)d_in[7];
    const float* w2 = (const float*)d_in[8];
    const float* b2 = (const float*)d_in[9];
    const float* w3 = (const float*)d_in[10];
    const float* b3 = (const float*)d_in[11];
    float* out = (float*)d_out;

    float* ws = (float*)d_ws;
    float* f1   = ws + OFF_F1;
    float* f2   = ws + OFF_F2;
    float* f3   = ws + OFF_F3;   // overlaps f1 (f1 dead after conv2)
    float* geom = ws + OFF_GEOM;
    float* w1t  = ws + OFF_W1T;
    float* w2t  = ws + OFF_W2T;
    float* w3t  = ws + OFF_W3T;

    geom_kernel<<<1, 64, 0, stream>>>(poses, K, geom);
    tw_kernel<<<(C1*3*7*7 + 255)/256, 256, 0, stream>>>(w1, w1t, C1, 3, 7, 7);
    tw_kernel<<<(C_*C1*3*3 + 255)/256, 256, 0, stream>>>(w2, w2t, C_, C1, 3, 3);
    tw_kernel<<<(C_*C_*3*3 + 255)/256, 256, 0, stream>>>(w3, w3t, C_, C_, 3, 3);

    conv1_kernel<<<dim3(W2/16, H2/16, NIMG), dim3(16,16), 0, stream>>>(ref_img, ngh_img, w1t, b1, f1);
    conv2_kernel<<<dim3(W4/16, (H4+15)/16, NIMG), dim3(16,16), 0, stream>>>(f1, w2t, b2, f2);
    conv3_kernel<<<dim3(W4/16, (H4+15)/16, NIMG), dim3(16,16), 0, stream>>>(f2, w3t, b3, f3);

    warpcost_kernel<<<(B_*H4*W4)/4, 256, 0, stream>>>(f3, geom, dc, is_valid, out);
}

// Round 3
// 658.344 us; speedup vs baseline: 1.6043x; 1.6043x over previous
//
#include <hip/hip_runtime.h>
#include <hip/hip_bf16.h>

// Problem constants
#define B_  2
#define V_  4
#define Hin 480
#define Win 640
#define H2  240   // after conv1 (s2)
#define W2  320
#define H4  120   // after conv2 (s2)
#define W4  160
#define C1  32
#define C_  64
#define D_  5
#define NIMG 10  // B + B*V

// ---------------- workspace layout (float offsets) ----------------
#define OFF_F1   0
#define OFF_F2   24576000
#define OFF_F3   0
#define OFF_GEOM 36864000
#define OFF_W1T  36864128
#define OFF_W2T  36868864
#define OFF_W3T  36887296

// ---------------- weight transpose: [co][ci][kh][kw] -> [ci][kh][kw][co] ----
__global__ void tw_kernel(const float* __restrict__ w, float* __restrict__ wt,
                          int CO, int CI, int KH, int KW) {
    int idx = blockIdx.x * 256 + threadIdx.x;
    int total = CO * CI * KH * KW;
    if (idx >= total) return;
    int co = idx % CO;
    int r = idx / CO;
    int kx = r % KW; r /= KW;
    int ky = r % KH; r /= KH;
    int ci = r;
    wt[idx] = w[((co * CI + ci) * KH + ky) * KW + kx];
}

// ---------------- geometry: A = K R Kinv, c = K t ----------------
__global__ void geom_kernel(const float* __restrict__ poses,
                            const float* __restrict__ Kmat,
                            float* __restrict__ geom) {
    int i = threadIdx.x;         // (b*V + v)
    if (i >= B_ * V_) return;
    int b = i / V_;
    const float* Kb = Kmat + b * 9;
    float k00=Kb[0],k01=Kb[1],k02=Kb[2];
    float k10=Kb[3],k11=Kb[4],k12=Kb[5];
    float k20=Kb[6],k21=Kb[7],k22=Kb[8];
    float det = k00*(k11*k22-k12*k21) - k01*(k10*k22-k12*k20) + k02*(k10*k21-k11*k20);
    float id = 1.0f / det;
    float ki[9];
    ki[0]=(k11*k22-k12*k21)*id; ki[1]=(k02*k21-k01*k22)*id; ki[2]=(k01*k12-k02*k11)*id;
    ki[3]=(k12*k20-k10*k22)*id; ki[4]=(k00*k22-k02*k20)*id; ki[5]=(k02*k10-k00*k12)*id;
    ki[6]=(k10*k21-k11*k20)*id; ki[7]=(k01*k20-k00*k21)*id; ki[8]=(k00*k11-k01*k10)*id;
    const float* P = poses + i * 16;
    float R[9] = {P[0],P[1],P[2], P[4],P[5],P[6], P[8],P[9],P[10]};
    float t[3] = {P[3],P[7],P[11]};
    float KR[9];
    for (int r = 0; r < 3; r++)
        for (int c = 0; c < 3; c++)
            KR[r*3+c] = Kb[r*3+0]*R[0*3+c] + Kb[r*3+1]*R[1*3+c] + Kb[r*3+2]*R[2*3+c];
    float* g = geom + i * 12;
    for (int r = 0; r < 3; r++)
        for (int c = 0; c < 3; c++)
            g[r*3+c] = KR[r*3+0]*ki[0*3+c] + KR[r*3+1]*ki[1*3+c] + KR[r*3+2]*ki[2*3+c];
    for (int r = 0; r < 3; r++)
        g[9+r] = Kb[r*3+0]*t[0] + Kb[r*3+1]*t[1] + Kb[r*3+2]*t[2];
}

// ---------------- conv1: 3->32, 7x7, s2, p3, ReLU. out NCHW ----------------
// 16 out-channels per thread; blockIdx.z = n*2 + chunk
__global__ void conv1_kernel(const float* __restrict__ ref, const float* __restrict__ ngh,
                             const float* __restrict__ w1t, const float* __restrict__ b1,
                             float* __restrict__ out) {
    const int ox = blockIdx.x * 16 + threadIdx.x;
    const int oy = blockIdx.y * 16 + threadIdx.y;
    const int n  = blockIdx.z >> 1;
    const int c0 = (blockIdx.z & 1) * 16;
    const float* in = (n < B_) ? (ref + (size_t)n * 3 * Hin * Win)
                               : (ngh + (size_t)(n - B_) * 3 * Hin * Win);
    float acc[16];
#pragma unroll
    for (int i = 0; i < 16; i++) acc[i] = b1[c0 + i];
    for (int ci = 0; ci < 3; ci++) {
        for (int ky = 0; ky < 7; ky++) {
            int iy = oy * 2 - 3 + ky;
            if (iy < 0 || iy >= Hin) continue;
            const float* row = in + ((size_t)ci * Hin + iy) * Win;
            for (int kx = 0; kx < 7; kx++) {
                int ix = ox * 2 - 3 + kx;
                float val = (ix >= 0 && ix < Win) ? row[ix] : 0.0f;
                const float* wp = w1t + ((ci * 7 + ky) * 7 + kx) * C1 + c0;
#pragma unroll
                for (int i = 0; i < 16; i++) acc[i] += val * wp[i];
            }
        }
    }
#pragma unroll
    for (int i = 0; i < 16; i++)
        out[(((size_t)n * C1 + c0 + i) * H2 + oy) * W2 + ox] = fmaxf(acc[i], 0.0f);
}

// ---------------- conv2: 32->64, 3x3, s2, p1, ReLU. out NCHW ----------------
// 16 out-channels per thread; blockIdx.z = n*4 + chunk
__global__ void conv2_kernel(const float* __restrict__ in, const float* __restrict__ w2t,
                             const float* __restrict__ b2, float* __restrict__ out) {
    const int ox = blockIdx.x * 16 + threadIdx.x;
    const int oy = blockIdx.y * 16 + threadIdx.y;
    const int n  = blockIdx.z >> 2;
    const int c0 = (blockIdx.z & 3) * 16;
    if (oy >= H4) return;
    const float* inp = in + (size_t)n * C1 * H2 * W2;
    float acc[16];
#pragma unroll
    for (int i = 0; i < 16; i++) acc[i] = b2[c0 + i];
    for (int ci = 0; ci < C1; ci++) {
        const float* icp = inp + (size_t)ci * H2 * W2;
#pragma unroll
        for (int ky = 0; ky < 3; ky++) {
            int iy = oy * 2 - 1 + ky;
            if (iy < 0 || iy >= H2) continue;
            const float* row = icp + (size_t)iy * W2;
#pragma unroll
            for (int kx = 0; kx < 3; kx++) {
                int ix = ox * 2 - 1 + kx;
                float val = (ix >= 0 && ix < W2) ? row[ix] : 0.0f;
                const float* wp = w2t + ((ci * 3 + ky) * 3 + kx) * C_ + c0;
#pragma unroll
                for (int i = 0; i < 16; i++) acc[i] += val * wp[i];
            }
        }
    }
#pragma unroll
    for (int i = 0; i < 16; i++)
        out[(((size_t)n * C_ + c0 + i) * H4 + oy) * W4 + ox] = fmaxf(acc[i], 0.0f);
}

// ---------------- conv3: 64->64, 3x3, s1, p1, no act. out NHWC --------------
// 16 out-channels per thread; blockIdx.z = n*4 + chunk
__global__ void conv3_kernel(const float* __restrict__ in, const float* __restrict__ w3t,
                             const float* __restrict__ b3, float* __restrict__ out) {
    const int ox = blockIdx.x * 16 + threadIdx.x;
    const int oy = blockIdx.y * 16 + threadIdx.y;
    const int n  = blockIdx.z >> 2;
    const int c0 = (blockIdx.z & 3) * 16;
    if (oy >= H4) return;
    const float* inp = in + (size_t)n * C_ * H4 * W4;
    float acc[16];
#pragma unroll
    for (int i = 0; i < 16; i++) acc[i] = b3[c0 + i];
    for (int ci = 0; ci < C_; ci++) {
        const float* icp = inp + (size_t)ci * H4 * W4;
#pragma unroll
        for (int ky = 0; ky < 3; ky++) {
            int iy = oy - 1 + ky;
            if (iy < 0 || iy >= H4) continue;
            const float* row = icp + (size_t)iy * W4;
#pragma unroll
            for (int kx = 0; kx < 3; kx++) {
                int ix = ox - 1 + kx;
                float val = (ix >= 0 && ix < W4) ? row[ix] : 0.0f;
                const float* wp = w3t + ((ci * 3 + ky) * 3 + kx) * C_ + c0;
#pragma unroll
                for (int i = 0; i < 16; i++) acc[i] += val * wp[i];
            }
        }
    }
    float* op = out + (((size_t)n * H4 + oy) * W4 + ox) * C_ + c0;
#pragma unroll
    for (int i = 0; i < 16; i++) op[i] = acc[i];
}

// ---------------- warp + cost volume. one wave per (b,h,w) ----------------
__global__ void warpcost_kernel(const float* __restrict__ feat,  // NHWC, 10 imgs
                                const float* __restrict__ geom,
                                const float* __restrict__ dc,    // (B,D,H4,W4)
                                const int*   __restrict__ valid, // B*V ints
                                float* __restrict__ out) {
    const int wave = threadIdx.x >> 6;
    const int lane = threadIdx.x & 63;
    int pid = blockIdx.x * 4 + wave;  // 0 .. B*H4*W4-1
    int b = pid / (H4 * W4);
    int rem = pid % (H4 * W4);
    int h = rem / W4;
    int w = rem % W4;

    const float refc = feat[(((size_t)b * H4 + h) * W4 + w) * C_ + lane];

    float accv[D_] = {0.f, 0.f, 0.f, 0.f, 0.f};
    float den[D_]  = {0.f, 0.f, 0.f, 0.f, 0.f};

    for (int v = 0; v < V_; v++) {
        if (!valid[b * V_ + v]) continue;
        const float* g = geom + (b * V_ + v) * 12;
        float rx = g[0] * w + g[1] * h + g[2];
        float ry = g[3] * w + g[4] * h + g[5];
        float rz = g[6] * w + g[7] * h + g[8];
        float c0 = g[9], c1 = g[10], c2 = g[11];
        const float* fimg = feat + (size_t)(B_ + b * V_ + v) * H4 * W4 * C_;
#pragma unroll
        for (int d = 0; d < D_; d++) {
            float dep = dc[(((size_t)b * D_ + d) * H4 + h) * W4 + w];
            float px = dep * rx + c0;
            float py = dep * ry + c1;
            float pz = dep * rz + c2;
            bool zok = pz > 0.001f;
            float zc = fmaxf(pz, 0.001f);
            float u  = px / zc;
            float vv = py / zc;
            bool inb = (u >= 0.f) && (u <= (float)(W4 - 1)) &&
                       (vv >= 0.f) && (vv <= (float)(H4 - 1));
            if (zok && inb) {   // wave-uniform branch
                float u0f = floorf(u), v0f = floorf(vv);
                float du = u - u0f, dv = vv - v0f;
                int u0 = (int)u0f, v0 = (int)v0f;
                int u1 = min(u0 + 1, W4 - 1), v1 = min(v0 + 1, H4 - 1);
                const float* r00 = fimg + ((size_t)v0 * W4 + u0) * C_;
                const float* r01 = fimg + ((size_t)v0 * W4 + u1) * C_;
                const float* r10 = fimg + ((size_t)v1 * W4 + u0) * C_;
                const float* r11 = fimg + ((size_t)v1 * W4 + u1) * C_;
                float f00 = r00[lane], f01 = r01[lane];
                float f10 = r10[lane], f11 = r11[lane];
                float wa = (1.f - du) * (1.f - dv);
                float wb = du * (1.f - dv);
                float wc = (1.f - du) * dv;
                float wd = du * dv;
                accv[d] += f00 * wa + f01 * wb + f10 * wc + f11 * wd;
                den[d]  += 1.f;
            }
        }
    }

#pragma unroll
    for (int d = 0; d < D_; d++) {
        float s = refc * accv[d];
        for (int off = 32; off > 0; off >>= 1) s += __shfl_xor(s, off, 64);
        if (lane == 0) {
            out[(((size_t)b * D_ + d) * H4 + h) * W4 + w] =
                (s * (1.0f / (float)C_)) / fmaxf(den[d], 1.0f);
        }
    }
}

extern "C" void kernel_launch(void* const* d_in, const int* in_sizes, int n_in,
                              void* d_out, int out_size, void* d_ws, size_t ws_size,
                              hipStream_t stream) {
    const float* ref_img  = (const float*)d_in[0];
    const float* ngh_img  = (const float*)d_in[1];
    const float* poses    = (const float*)d_in[2];
    const int*   is_valid = (const int*)  d_in[3];
    const float* K        = (const float*)d_in[4];
    const float* dc       = (const float*)d_in[5];
    const float* w1 = (const float*)d_in[6];
    const float* b1 = (const float*)d_in[7];
    const float* w2 = (const float*)d_in[8];
    const float* b2 = (const float*)d_in[9];
    const float* w3 = (const float*)d_in[10];
    const float* b3 = (const float*)d_in[11];
    float* out = (float*)d_out;

    float* ws = (float*)d_ws;
    float* f1   = ws + OFF_F1;
    float* f2   = ws + OFF_F2;
    float* f3   = ws + OFF_F3;   // overlaps f1 (f1 dead after conv2)
    float* geom = ws + OFF_GEOM;
    float* w1t  = ws + OFF_W1T;
    float* w2t  = ws + OFF_W2T;
    float* w3t  = ws + OFF_W3T;

    geom_kernel<<<1, 64, 0, stream>>>(poses, K, geom);
    tw_kernel<<<(C1*3*7*7 + 255)/256, 256, 0, stream>>>(w1, w1t, C1, 3, 7, 7);
    tw_kernel<<<(C_*C1*3*3 + 255)/256, 256, 0, stream>>>(w2, w2t, C_, C1, 3, 3);
    tw_kernel<<<(C_*C_*3*3 + 255)/256, 256, 0, stream>>>(w3, w3t, C_, C_, 3, 3);

    conv1_kernel<<<dim3(W2/16, H2/16, NIMG*2), dim3(16,16), 0, stream>>>(ref_img, ngh_img, w1t, b1, f1);
    conv2_kernel<<<dim3(W4/16, (H4+15)/16, NIMG*4), dim3(16,16), 0, stream>>>(f1, w2t, b2, f2);
    conv3_kernel<<<dim3(W4/16, (H4+15)/16, NIMG*4), dim3(16,16), 0, stream>>>(f2, w3t, b3, f3);

    warpcost_kernel<<<(B_*H4*W4)/4, 256, 0, stream>>>(f3, geom, dc, is_valid, out);
}